// Round 1
// baseline (887.915 us; speedup 1.0000x reference)
//
#include <hip/hip_runtime.h>

typedef __bf16 bf16;
typedef __bf16 bf16x8 __attribute__((ext_vector_type(8)));
typedef float  f32x4  __attribute__((ext_vector_type(4)));

#define NB 4
#define NT 2048
#define NC 512
#define NV 32000
#define NROWS (NB*NT)          // 8192
#define NCHUNK (NV/128)        // 250
#define LNEPS 1e-5f

static __device__ __forceinline__ void load_lds16(const bf16* g, bf16* l) {
  __builtin_amdgcn_global_load_lds(
      (const __attribute__((address_space(1))) void*)g,
      (__attribute__((address_space(3))) void*)l, 16, 0, 0);
}

// ---------------- f32 -> bf16 convert (vectorized x8) ----------------
__global__ __launch_bounds__(256)
void cvt_kernel(const float* __restrict__ in, bf16* __restrict__ out, int n8) {
  long i = (long)blockIdx.x * 256 + threadIdx.x;
  long stride = (long)gridDim.x * 256;
  for (; i < n8; i += stride) {
    const float* p = in + i * 8;
    f32x4 a = *(const f32x4*)p;
    f32x4 b = *(const f32x4*)(p + 4);
    bf16x8 o;
    o[0]=(bf16)a.x; o[1]=(bf16)a.y; o[2]=(bf16)a.z; o[3]=(bf16)a.w;
    o[4]=(bf16)b.x; o[5]=(bf16)b.y; o[6]=(bf16)b.z; o[7]=(bf16)b.w;
    *(bf16x8*)(out + i*8) = o;
  }
}

// ---------------- embedding: x0 = tok_emb[idx] + pos_emb[t] ----------------
__global__ __launch_bounds__(64)
void embed_kernel(const int* __restrict__ idx, const float* __restrict__ tok,
                  const float* __restrict__ pos, float* __restrict__ x0) {
  int row = blockIdx.x;          // 0..8191
  int t = row & (NT-1);
  int id = idx[row];
  int lane = threadIdx.x;        // 64 lanes * 8 f32 = 512
  const float* tr = tok + (long)id*NC + lane*8;
  const float* pr = pos + (long)t*NC + lane*8;
  f32x4 a0 = *(const f32x4*)tr, a1 = *(const f32x4*)(tr+4);
  f32x4 p0 = *(const f32x4*)pr, p1 = *(const f32x4*)(pr+4);
  f32x4 r0 = a0 + p0, r1 = a1 + p1;
  float* o = x0 + (long)row*NC + lane*8;
  *(f32x4*)o = r0; *(f32x4*)(o+4) = r1;
}

// ---------------- layernorm: one wave per row of 512 ----------------
__global__ __launch_bounds__(64)
void ln_kernel(const float* __restrict__ x, const float* __restrict__ gw,
               const float* __restrict__ bw, bf16* __restrict__ out) {
  int row = blockIdx.x;
  int lane = threadIdx.x;
  const float* xr = x + (long)row*NC + lane*8;
  f32x4 a = *(const f32x4*)xr;
  f32x4 b = *(const f32x4*)(xr+4);
  float v[8] = {a.x,a.y,a.z,a.w,b.x,b.y,b.z,b.w};
  float s = 0.f;
  #pragma unroll
  for (int j=0;j<8;++j) s += v[j];
  #pragma unroll
  for (int m=32;m>=1;m>>=1) s += __shfl_xor(s, m);
  float mu = s * (1.f/NC);
  float sq = 0.f;
  #pragma unroll
  for (int j=0;j<8;++j) { v[j] -= mu; sq += v[j]*v[j]; }
  #pragma unroll
  for (int m=32;m>=1;m>>=1) sq += __shfl_xor(sq, m);
  float rs = rsqrtf(sq * (1.f/NC) + LNEPS);
  const float* gp = gw + lane*8;
  const float* bp = bw + lane*8;
  f32x4 g0 = *(const f32x4*)gp, g1 = *(const f32x4*)(gp+4);
  f32x4 b0 = *(const f32x4*)bp, b1 = *(const f32x4*)(bp+4);
  float gg[8] = {g0.x,g0.y,g0.z,g0.w,g1.x,g1.y,g1.z,g1.w};
  float bb[8] = {b0.x,b0.y,b0.z,b0.w,b1.x,b1.y,b1.z,b1.w};
  bf16x8 o;
  #pragma unroll
  for (int j=0;j<8;++j) o[j] = (bf16)(v[j]*rs*gg[j] + bb[j]);
  *(bf16x8*)(out + (long)row*NC + lane*8) = o;
}

// ---------------- transpose v[b][t][c] -> vt[b][c][t] ----------------
__global__ __launch_bounds__(256)
void transpose_kernel(const bf16* __restrict__ v, bf16* __restrict__ vt) {
  __shared__ bf16 tile[64][66];
  int b = blockIdx.z;
  int t0 = blockIdx.x*64, c0 = blockIdx.y*64;
  int tid = threadIdx.x;
  int r = tid >> 2, ch = (tid & 3) * 16;
  const bf16* src = v + ((long)b*NT + t0 + r)*NC + c0 + ch;
  #pragma unroll
  for (int i=0;i<16;++i) tile[r][ch+i] = src[i];
  __syncthreads();
  bf16x8 o0, o1;
  #pragma unroll
  for (int i=0;i<8;++i) o0[i] = tile[ch+i][r];
  #pragma unroll
  for (int i=0;i<8;++i) o1[i] = tile[ch+8+i][r];
  bf16* dst = vt + ((long)b*NC + c0 + r)*NT + t0 + ch;
  *(bf16x8*)dst = o0;
  *(bf16x8*)(dst+8) = o1;
}

// ---------------- causal softmax row: S f32 -> P bf16 (aliased into S) ----------------
__global__ __launch_bounds__(256)
void softmax_kernel(float* __restrict__ S) {
  const int row = blockIdx.x;          // b*NT + t
  const int t = row & (NT-1);
  const int tid = threadIdx.x;
  float* sr = S + (long)row*NT;
  bf16* pr = (bf16*)S + (long)row*(2*NT);   // row stride 4096 bf16 = 8192B (same bytes as S row)
  const float scale = 0.044194173824159216f;
  f32x4 v0 = *(const f32x4*)(sr + tid*8);
  f32x4 v1 = *(const f32x4*)(sr + tid*8 + 4);
  float v[8] = {v0.x,v0.y,v0.z,v0.w,v1.x,v1.y,v1.z,v1.w};
  int cb = tid*8;
  float mx = -1e30f;
  #pragma unroll
  for (int j=0;j<8;++j) {
    v[j] = (cb + j <= t) ? v[j]*scale : -1e30f;
    mx = fmaxf(mx, v[j]);
  }
  __shared__ float redm[4];
  #pragma unroll
  for (int m=32;m>=1;m>>=1) mx = fmaxf(mx, __shfl_xor(mx, m));
  if ((tid & 63) == 0) redm[tid>>6] = mx;
  __syncthreads();
  mx = fmaxf(fmaxf(redm[0],redm[1]), fmaxf(redm[2],redm[3]));
  float e[8]; float s = 0.f;
  #pragma unroll
  for (int j=0;j<8;++j) { e[j] = (cb + j <= t) ? __expf(v[j]-mx) : 0.f; s += e[j]; }
  __shared__ float reds[4];
  #pragma unroll
  for (int m=32;m>=1;m>>=1) s += __shfl_xor(s, m);
  if ((tid & 63) == 0) reds[tid>>6] = s;
  __syncthreads();
  s = reds[0]+reds[1]+reds[2]+reds[3];
  float inv = 1.f/s;
  bf16x8 o;
  #pragma unroll
  for (int j=0;j<8;++j) o[j] = (bf16)(e[j]*inv);
  *(bf16x8*)(pr + cb) = o;
}

// ---------------- GEMM: out[M,N] = A[M,K] * B[N,K]^T, 128x128 tile ----------------
enum { EPI_F32=0, EPI_BF16=1, EPI_BIAS_RELU_BF16=2, EPI_BIAS_RES_BF16=3, EPI_RES_F32=4, EPI_LMHEAD=5 };

template<int EPI>
__global__ __launch_bounds__(256)
void gemm_bt(const bf16* __restrict__ A, const bf16* __restrict__ B, int K,
             long lda, long ldb, long sAb, long sBb,
             float* __restrict__ outf, bf16* __restrict__ outb, long ldo, long sOb,
             const float* __restrict__ bias,
             const float* __restrict__ res, long ldr, long sRb,
             float* __restrict__ pmax, float* __restrict__ psum, int nchunk) {
  __shared__ bf16 As[128*32] __attribute__((aligned(16)));
  __shared__ bf16 Bs[128*32] __attribute__((aligned(16)));
  const int tid = threadIdx.x;
  const int wave = tid >> 6;
  const int lane = tid & 63;
  const int bm = blockIdx.y, bn = blockIdx.x, bz = blockIdx.z;
  const int wr = wave >> 1, wc = wave & 1;
  const int l15 = lane & 15, g = lane >> 4;

  const bf16* Ab = A + (long)bz*sAb + (long)bm*128*lda;
  const bf16* Bb = B + (long)bz*sBb + (long)bn*128*ldb;

  f32x4 acc[4][4] = {};

  const int r0 = tid >> 2,          c0 = tid & 3;
  const int r1 = (256+tid) >> 2,    c1 = tid & 3;   // (256+tid)&3 == tid&3
  bf16* lA0 = As + (wave*64)*8;
  bf16* lB0 = Bs + (wave*64)*8;
  bf16* lA1 = As + (256 + wave*64)*8;
  bf16* lB1 = Bs + (256 + wave*64)*8;

  for (int k0 = 0; k0 < K; k0 += 32) {
    __syncthreads();
    load_lds16(Ab + (long)r0*lda + k0 + c0*8, lA0);
    load_lds16(Bb + (long)r0*ldb + k0 + c0*8, lB0);
    load_lds16(Ab + (long)r1*lda + k0 + c1*8, lA1);
    load_lds16(Bb + (long)r1*ldb + k0 + c1*8, lB1);
    __syncthreads();
    bf16x8 af[4], bfr[4];
    #pragma unroll
    for (int m=0;m<4;++m)
      af[m] = *(const bf16x8*)(As + ((wr*64 + m*16 + l15)*32 + g*8));
    #pragma unroll
    for (int n=0;n<4;++n)
      bfr[n] = *(const bf16x8*)(Bs + ((wc*64 + n*16 + l15)*32 + g*8));
    #pragma unroll
    for (int m=0;m<4;++m)
      #pragma unroll
      for (int n=0;n<4;++n)
        acc[m][n] = __builtin_amdgcn_mfma_f32_16x16x32_bf16(af[m], bfr[n], acc[m][n], 0, 0, 0);
  }

  const long rowbase = (long)bm*128 + wr*64;
  const long colbase = (long)bn*128 + wc*64;

  if constexpr (EPI == EPI_LMHEAD) {
    __shared__ float redm[2][128];
    __shared__ float reds[2][128];
    // add bias, store logits
    #pragma unroll
    for (int m=0;m<4;++m) {
      #pragma unroll
      for (int n=0;n<4;++n) {
        long c = colbase + n*16 + l15;
        float bv = bias[c];
        #pragma unroll
        for (int reg=0;reg<4;++reg) {
          acc[m][n][reg] += bv;
          long rr = rowbase + m*16 + g*4 + reg;
          outf[rr*ldo + c] = acc[m][n][reg];
        }
      }
    }
    // per-row (max, sumexp) over this block's 128 cols
    #pragma unroll
    for (int m=0;m<4;++m) {
      #pragma unroll
      for (int reg=0;reg<4;++reg) {
        float mx = -1e30f;
        #pragma unroll
        for (int n=0;n<4;++n) mx = fmaxf(mx, acc[m][n][reg]);
        #pragma unroll
        for (int msk=8;msk>=1;msk>>=1) mx = fmaxf(mx, __shfl_xor(mx, msk));
        float se = 0.f;
        #pragma unroll
        for (int n=0;n<4;++n) se += __expf(acc[m][n][reg] - mx);
        #pragma unroll
        for (int msk=8;msk>=1;msk>>=1) se += __shfl_xor(se, msk);
        if (l15 == 0) {
          int lr = wr*64 + m*16 + g*4 + reg;
          redm[wc][lr] = mx;
          reds[wc][lr] = se;
        }
      }
    }
    __syncthreads();
    if (tid < 128) {
      float m0 = redm[0][tid], m1 = redm[1][tid];
      float M = fmaxf(m0, m1);
      float Sv = reds[0][tid]*__expf(m0 - M) + reds[1][tid]*__expf(m1 - M);
      long row = (long)bm*128 + tid;
      pmax[row*nchunk + bn] = M;
      psum[row*nchunk + bn] = Sv;
    }
  } else {
    #pragma unroll
    for (int m=0;m<4;++m) {
      #pragma unroll
      for (int n=0;n<4;++n) {
        long c = colbase + n*16 + l15;
        #pragma unroll
        for (int reg=0;reg<4;++reg) {
          long rr = rowbase + m*16 + g*4 + reg;
          float v = acc[m][n][reg];
          if constexpr (EPI == EPI_F32) {
            outf[(long)bz*sOb + rr*ldo + c] = v;
          } else if constexpr (EPI == EPI_BF16) {
            outb[(long)bz*sOb + rr*ldo + c] = (bf16)v;
          } else if constexpr (EPI == EPI_BIAS_RELU_BF16) {
            v += bias[c];
            v = fmaxf(v, 0.f);
            outb[rr*ldo + c] = (bf16)v;
          } else if constexpr (EPI == EPI_BIAS_RES_BF16) {
            v += bias[c] + res[rr*ldr + c];
            outb[rr*ldo + c] = (bf16)v;
          } else if constexpr (EPI == EPI_RES_F32) {
            v += res[(long)bz*sRb + rr*ldr + c];
            outf[(long)bz*sOb + rr*ldo + c] = v;
          }
        }
      }
    }
  }
}

// ---------------- loss pass 1: per-row lse + target gather ----------------
__global__ __launch_bounds__(256)
void loss1_kernel(const float* __restrict__ pmax, const float* __restrict__ psum,
                  const float* __restrict__ logits, const int* __restrict__ targets,
                  float* __restrict__ rowloss) {
  int row = blockIdx.x;
  int tid = threadIdx.x;
  int lane = tid & 63, wv = tid >> 6;
  float cm = (tid < NCHUNK) ? pmax[(long)row*NCHUNK + tid] : -1e30f;
  float cs = (tid < NCHUNK) ? psum[(long)row*NCHUNK + tid] : 0.f;
  float mx = cm;
  #pragma unroll
  for (int m=32;m>=1;m>>=1) mx = fmaxf(mx, __shfl_xor(mx, m));
  __shared__ float rm[4];
  if (lane == 0) rm[wv] = mx;
  __syncthreads();
  float M = fmaxf(fmaxf(rm[0],rm[1]), fmaxf(rm[2],rm[3]));
  float sc = cs * __expf(cm - M);
  #pragma unroll
  for (int m=32;m>=1;m>>=1) sc += __shfl_xor(sc, m);
  __shared__ float rs_[4];
  if (lane == 0) rs_[wv] = sc;
  __syncthreads();
  if (tid == 0) {
    float Sv = rs_[0]+rs_[1]+rs_[2]+rs_[3];
    float lse = M + logf(Sv);
    int tgt = targets[row];
    float lg = logits[(long)row*NV + tgt];
    rowloss[row] = lse - lg;
  }
}

// ---------------- loss pass 2: mean over rows ----------------
__global__ __launch_bounds__(256)
void loss2_kernel(const float* __restrict__ rowloss, float* __restrict__ out) {
  int tid = threadIdx.x;
  float s = 0.f;
  for (int i = tid; i < NROWS; i += 256) s += rowloss[i];
  #pragma unroll
  for (int m=32;m>=1;m>>=1) s += __shfl_xor(s, m);
  __shared__ float rs_[4];
  if ((tid & 63) == 0) rs_[tid>>6] = s;
  __syncthreads();
  if (tid == 0) out[0] = (rs_[0]+rs_[1]+rs_[2]+rs_[3]) * (1.f/NROWS);
}

// ---------------- launcher ----------------
extern "C" void kernel_launch(void* const* d_in, const int* in_sizes, int n_in,
                              void* d_out, int out_size, void* d_ws, size_t ws_size,
                              hipStream_t stream) {
  const int*   idx  = (const int*)d_in[0];
  const int*   tgt  = (const int*)d_in[1];
  const float* tok  = (const float*)d_in[2];
  const float* pos  = (const float*)d_in[3];
  const float* Wk   = (const float*)d_in[4];
  const float* Wq   = (const float*)d_in[5];
  const float* Wv   = (const float*)d_in[6];
  const float* W1   = (const float*)d_in[7];
  const float* b1   = (const float*)d_in[8];
  const float* W2   = (const float*)d_in[9];
  const float* b2   = (const float*)d_in[10];
  const float* g1   = (const float*)d_in[11];
  const float* be1  = (const float*)d_in[12];
  const float* g2   = (const float*)d_in[13];
  const float* be2  = (const float*)d_in[14];
  const float* Wlm  = (const float*)d_in[15];
  const float* blm  = (const float*)d_in[16];

  float* logits = (float*)d_out;
  float* loss   = logits + (long)NROWS*NV;

  char* w = (char*)d_ws;
  auto alloc = [&](size_t bytes) -> char* {
    char* p = w; w += (bytes + 255) & ~(size_t)255; return p;
  };
  bf16* wqb  = (bf16*)alloc((size_t)NC*NC*2);
  bf16* wkb  = (bf16*)alloc((size_t)NC*NC*2);
  bf16* wvb  = (bf16*)alloc((size_t)NC*NC*2);
  bf16* w1b  = (bf16*)alloc((size_t)4*NC*NC*2);
  bf16* w2b  = (bf16*)alloc((size_t)4*NC*NC*2);
  bf16* wlmb = (bf16*)alloc((size_t)NV*NC*2);
  float* x0  = (float*)alloc((size_t)NROWS*NC*4);
  bf16* h1b  = (bf16*)alloc((size_t)NROWS*NC*2);
  bf16* qb   = (bf16*)alloc((size_t)NROWS*NC*2);
  bf16* kb   = (bf16*)alloc((size_t)NROWS*NC*2);
  bf16* vb   = (bf16*)alloc((size_t)NROWS*NC*2);
  bf16* vtb  = (bf16*)alloc((size_t)NROWS*NC*2);
  float* Sb  = (float*)alloc((size_t)NB*NT*NT*4);   // P (bf16) aliased inside
  float* x1  = (float*)alloc((size_t)NROWS*NC*4);
  bf16* h2b  = (bf16*)alloc((size_t)NROWS*NC*2);
  bf16* ffb  = (bf16*)alloc((size_t)NROWS*4*NC*2);
  bf16* x2b  = (bf16*)alloc((size_t)NROWS*NC*2);
  float* pmax = (float*)alloc((size_t)NROWS*NCHUNK*4);
  float* psum = (float*)alloc((size_t)NROWS*NCHUNK*4);
  float* rowloss = (float*)alloc((size_t)NROWS*4);

  auto cvt = [&](const float* in, bf16* out, long n) {
    int n8 = (int)(n/8);
    int blocks = (n8 + 255)/256; if (blocks > 2048) blocks = 2048;
    cvt_kernel<<<blocks, 256, 0, stream>>>(in, out, n8);
  };
  cvt(Wq, wqb, (long)NC*NC);
  cvt(Wk, wkb, (long)NC*NC);
  cvt(Wv, wvb, (long)NC*NC);
  cvt(W1, w1b, (long)4*NC*NC);
  cvt(W2, w2b, (long)4*NC*NC);
  cvt(Wlm, wlmb, (long)NV*NC);

  embed_kernel<<<NROWS, 64, 0, stream>>>(idx, tok, pos, x0);
  ln_kernel<<<NROWS, 64, 0, stream>>>(x0, g1, be1, h1b);

  // QKV
  gemm_bt<EPI_BF16><<<dim3(4,64,1), 256, 0, stream>>>(
      h1b, wqb, NC, NC, NC, 0, 0, nullptr, qb, NC, 0,
      nullptr, nullptr, 0, 0, nullptr, nullptr, 0);
  gemm_bt<EPI_BF16><<<dim3(4,64,1), 256, 0, stream>>>(
      h1b, wkb, NC, NC, NC, 0, 0, nullptr, kb, NC, 0,
      nullptr, nullptr, 0, 0, nullptr, nullptr, 0);
  gemm_bt<EPI_BF16><<<dim3(4,64,1), 256, 0, stream>>>(
      h1b, wvb, NC, NC, NC, 0, 0, nullptr, vb, NC, 0,
      nullptr, nullptr, 0, 0, nullptr, nullptr, 0);

  transpose_kernel<<<dim3(NT/64, NC/64, NB), 256, 0, stream>>>(vb, vtb);

  // S = q k^T (per batch)
  gemm_bt<EPI_F32><<<dim3(16,16,NB), 256, 0, stream>>>(
      qb, kb, NC, NC, NC, (long)NT*NC, (long)NT*NC,
      Sb, nullptr, NT, (long)NT*NT,
      nullptr, nullptr, 0, 0, nullptr, nullptr, 0);

  softmax_kernel<<<NROWS, 256, 0, stream>>>(Sb);

  // x1 = x0 + P vT^T (per batch); P aliased in Sb, row stride 4096 bf16
  gemm_bt<EPI_RES_F32><<<dim3(4,16,NB), 256, 0, stream>>>(
      (const bf16*)Sb, vtb, NT, 2*NT, NT, (long)NT*2*NT, (long)NC*NT,
      x1, nullptr, NC, (long)NT*NC,
      nullptr, x0, NC, (long)NT*NC, nullptr, nullptr, 0);

  ln_kernel<<<NROWS, 64, 0, stream>>>(x1, g2, be2, h2b);

  // ff = relu(h2 W1^T + b1)
  gemm_bt<EPI_BIAS_RELU_BF16><<<dim3(16,64,1), 256, 0, stream>>>(
      h2b, w1b, NC, NC, NC, 0, 0, nullptr, ffb, 4*NC, 0,
      b1, nullptr, 0, 0, nullptr, nullptr, 0);

  // x2 = x1 + ff W2^T + b2  (bf16 out)
  gemm_bt<EPI_BIAS_RES_BF16><<<dim3(4,64,1), 256, 0, stream>>>(
      ffb, w2b, 4*NC, 4*NC, 4*NC, 0, 0, nullptr, x2b, NC, 0,
      b2, x1, NC, 0, nullptr, nullptr, 0);

  // logits = x2 Wlm^T + blm, plus per-chunk (max,sumexp) partials
  gemm_bt<EPI_LMHEAD><<<dim3(NCHUNK,64,1), 256, 0, stream>>>(
      x2b, wlmb, NC, NC, NC, 0, 0, logits, nullptr, NV, 0,
      blm, nullptr, 0, 0, pmax, psum, NCHUNK);

  loss1_kernel<<<NROWS, 256, 0, stream>>>(pmax, psum, logits, tgt, rowloss);
  loss2_kernel<<<1, 256, 0, stream>>>(rowloss, loss);
}